// Round 10
// baseline (6185.332 us; speedup 1.0000x reference)
//
#include <hip/hip_runtime.h>
#include <hip/hip_bf16.h>
#include <math.h>

#define E_DIM 1024
#define H_DIM 2048
#define H3 6144
#define VOCAB 256
#define NCOMP 256          // one WG per CU
#define TPW 512            // 8 waves; wave uu owns hidden unit base+uu

typedef unsigned long long u64;

// ---------------- Phase A: table[v][j] = b_ih[j] + sum_e emb[v,e]*w_ih[j,e]
__global__ __launch_bounds__(256) void ih_table_kernel(
    const float* __restrict__ emb, const float* __restrict__ w_ih,
    const float* __restrict__ b_ih, float* __restrict__ table)
{
    __shared__ float As[32][65];
    __shared__ float Bs[32][65];
    const int v0 = blockIdx.y * 64;
    const int j0 = blockIdx.x * 64;
    const int t  = threadIdx.x;
    const int tx = t % 16, ty = t / 16;
    const int lr0 = t / 8;
    const int lc  = (t % 8) * 4;
    float acc[4][4] = {};

    for (int k0 = 0; k0 < E_DIM; k0 += 32) {
        __syncthreads();
#pragma unroll
        for (int p = 0; p < 2; ++p) {
            int r = lr0 + p * 32;
            float4 a = *(const float4*)(emb  + (size_t)(v0 + r) * E_DIM + k0 + lc);
            As[lc+0][r] = a.x; As[lc+1][r] = a.y; As[lc+2][r] = a.z; As[lc+3][r] = a.w;
            float4 b = *(const float4*)(w_ih + (size_t)(j0 + r) * E_DIM + k0 + lc);
            Bs[lc+0][r] = b.x; Bs[lc+1][r] = b.y; Bs[lc+2][r] = b.z; Bs[lc+3][r] = b.w;
        }
        __syncthreads();
#pragma unroll 8
        for (int kk = 0; kk < 32; ++kk) {
            float a4[4], b4[4];
#pragma unroll
            for (int i = 0; i < 4; ++i) a4[i] = As[kk][ty * 4 + i];
#pragma unroll
            for (int i = 0; i < 4; ++i) b4[i] = Bs[kk][tx * 4 + i];
#pragma unroll
            for (int i = 0; i < 4; ++i)
#pragma unroll
                for (int j = 0; j < 4; ++j) acc[i][j] += a4[i] * b4[j];
        }
    }
    const int j = j0 + tx * 4;
    float4 bias = *(const float4*)(b_ih + j);
#pragma unroll
    for (int i = 0; i < 4; ++i) {
        int v = v0 + ty * 4 + i;
        float4 o;
        o.x = acc[i][0] + bias.x; o.y = acc[i][1] + bias.y;
        o.z = acc[i][2] + bias.z; o.w = acc[i][3] + bias.w;
        *(float4*)(table + (size_t)v * H3 + j) = o;
    }
}

// ---------------- Phase B: persistent GRU, W_hh register-resident (R7 base).
// h exchanged as u64 {tag:32 | f32 bits:32}; tag==s marks h_s valid.
// Wave uu owns unit base+uu end-to-end: dot in registers, 64-lane shuffle
// reduce, lane 0 computes gates and publishes immediately. ONE barrier per
// step; hsh double-buffered for wave slip. R10 change: DEPTH-2 INTERLEAVED
// POLL — sweeps A and B alternate in flight; checking A only drains A's
// vmcnt slots (B stays outstanding), halving the detection cadence vs
// load->wait->check->sleep. Sleep pacing retained (R9's sleepless spin +
// decorrelated arrivals doubled poll traffic and time).
__global__ __launch_bounds__(TPW, 2) void gru_persistent(
    const int* __restrict__ x, const int* __restrict__ lenp,
    const float* __restrict__ w_hh, const float* __restrict__ b_hh,
    const float* __restrict__ table,
    u64* hbuf0, u64* hbuf1)
{
    __shared__ float hsh[2][H_DIM];   // double-buffered staged h
    const int cw   = blockIdx.x;
    const int tid  = threadIdx.x;
    const int base = cw * 8;
    const int uu   = tid >> 6;     // wave id = owned unit
    const int l    = tid & 63;     // lane
    const int S    = lenp[0] + 1;  // 1025

    // one-time weight preload: 3 gates x 8 float4 = 96 regs (AGPR-backed),
    // pinned per-scalar against re-materialization
    float4 wv[3][8];
#pragma unroll
    for (int g = 0; g < 3; ++g) {
        const float4* wr =
            (const float4*)(w_hh + (size_t)(g * H_DIM + base + uu) * H_DIM);
#pragma unroll
        for (int i = 0; i < 8; ++i) wv[g][i] = wr[i * 64 + l];
    }
#pragma unroll
    for (int g = 0; g < 3; ++g)
#pragma unroll
        for (int i = 0; i < 8; ++i)
            asm volatile("" : "+v"(wv[g][i].x), "+v"(wv[g][i].y),
                              "+v"(wv[g][i].z), "+v"(wv[g][i].w));

    float bhr = 0.f, bhz = 0.f, bhn = 0.f;
    if (l == 0) {
        bhr = b_hh[base + uu];
        bhz = b_hh[H_DIM + base + uu];
        bhn = b_hh[2 * H_DIM + base + uu];
    }

    u64* bufs[2] = {hbuf0, hbuf1};

    for (int s = 0; s < S; ++s) {
        const u64* src = bufs[s & 1];
        u64*       dst = bufs[(s + 1) & 1];
        float*     hs  = hsh[s & 1];

        // input-side gate values: issue before the spin (latency overlaps)
        float ihr = 0.f, ihz = 0.f, ihn = 0.f;
        if (l == 0) {
            const float* trow = table + (size_t)x[s] * H3;
            ihr = trow[base + uu];
            ihz = trow[H_DIM + base + uu];
            ihn = trow[2 * H_DIM + base + uu];
        }

        // depth-2 interleaved poll+stage: discovering load IS the data load
        {
            const unsigned want = (unsigned)s;
            u64 A[4], B[4];
            bool ok[4] = {false, false, false, false};
#pragma unroll
            for (int j = 0; j < 4; ++j)
                A[j] = __hip_atomic_load(src + tid + j * TPW, __ATOMIC_RELAXED,
                                         __HIP_MEMORY_SCOPE_AGENT);
#pragma unroll
            for (int j = 0; j < 4; ++j)
                B[j] = __hip_atomic_load(src + tid + j * TPW, __ATOMIC_RELAXED,
                                         __HIP_MEMORY_SCOPE_AGENT);
            int rem = 4;
            for (;;) {
                // check sweep A (oldest); B remains in flight
#pragma unroll
                for (int j = 0; j < 4; ++j) {
                    if (!ok[j] && (unsigned)(A[j] >> 32) == want) {
                        ok[j] = true; --rem;
                        hs[tid + j * TPW] = __uint_as_float((unsigned)A[j]);
                    }
                }
                if (!rem) break;
#pragma unroll
                for (int j = 0; j < 4; ++j)       // reissue A
                    if (!ok[j])
                        A[j] = __hip_atomic_load(src + tid + j * TPW,
                                                 __ATOMIC_RELAXED,
                                                 __HIP_MEMORY_SCOPE_AGENT);
                // check sweep B
#pragma unroll
                for (int j = 0; j < 4; ++j) {
                    if (!ok[j] && (unsigned)(B[j] >> 32) == want) {
                        ok[j] = true; --rem;
                        hs[tid + j * TPW] = __uint_as_float((unsigned)B[j]);
                    }
                }
                if (!rem) break;
#pragma unroll
                for (int j = 0; j < 4; ++j)       // reissue B
                    if (!ok[j])
                        B[j] = __hip_atomic_load(src + tid + j * TPW,
                                                 __ATOMIC_RELAXED,
                                                 __HIP_MEMORY_SCOPE_AGENT);
                __builtin_amdgcn_s_sleep(1);
            }
        }
        __syncthreads();   // the ONLY barrier per step

        // fused-gate dot for unit base+uu: each h chunk read once, 3 FMAs
        const float4* h4 = (const float4*)hs;
        float4 ar = make_float4(0.f, 0.f, 0.f, 0.f);
        float4 az = make_float4(0.f, 0.f, 0.f, 0.f);
        float4 an = make_float4(0.f, 0.f, 0.f, 0.f);
#pragma unroll
        for (int i = 0; i < 8; ++i) {
            float4 hv = h4[i * 64 + l];
            ar.x += wv[0][i].x * hv.x; ar.y += wv[0][i].y * hv.y;
            ar.z += wv[0][i].z * hv.z; ar.w += wv[0][i].w * hv.w;
            az.x += wv[1][i].x * hv.x; az.y += wv[1][i].y * hv.y;
            az.z += wv[1][i].z * hv.z; az.w += wv[1][i].w * hv.w;
            an.x += wv[2][i].x * hv.x; an.y += wv[2][i].y * hv.y;
            an.z += wv[2][i].z * hv.z; an.w += wv[2][i].w * hv.w;
        }
        float pr = (ar.x + ar.y) + (ar.z + ar.w);
        float pz = (az.x + az.y) + (az.z + az.w);
        float pn = (an.x + an.y) + (an.z + an.w);
#pragma unroll
        for (int d = 1; d < 64; d <<= 1) {
            pr += __shfl_xor(pr, d);
            pz += __shfl_xor(pz, d);
            pn += __shfl_xor(pn, d);
        }

        // lane 0: gates + immediate publish
        if (l == 0) {
            float hprev = hs[base + uu];
            float hr = pr + bhr;
            float hz = pz + bhz;
            float hn = pn + bhn;
            float r_ = 1.f / (1.f + __expf(-(ihr + hr)));
            float z_ = 1.f / (1.f + __expf(-(ihz + hz)));
            float xn = ihn + r_ * hn;
            float axn = fabsf(xn), te = __expf(2.f * axn);
            float n_ = copysignf(1.f - 2.f / (te + 1.f), xn);
            float hnew = (1.f - z_) * n_ + z_ * hprev;
            u64 pack = ((u64)(unsigned)(s + 1) << 32) |
                       (u64)__float_as_uint(hnew);
            __hip_atomic_store(dst + base + uu, pack, __ATOMIC_RELAXED,
                               __HIP_MEMORY_SCOPE_AGENT);
        }
        // no trailing barrier: next step stages into the other hsh buffer
    }
}

// ---------------- Epilogue: out = [dec_emb[2] (1024) | h_final (2048)]
__global__ void epilogue_kernel(const int* __restrict__ lenp,
                                const float* __restrict__ dec_emb,
                                const u64* __restrict__ hbuf0,
                                const u64* __restrict__ hbuf1,
                                float* __restrict__ out)
{
    int i = blockIdx.x * blockDim.x + threadIdx.x;
    int S = lenp[0] + 1;
    const u64* hb = (S & 1) ? hbuf1 : hbuf0;
    if (i < E_DIM) out[i] = dec_emb[2 * E_DIM + i];
    else if (i < E_DIM + H_DIM)
        out[i] = __uint_as_float((unsigned)hb[i - E_DIM]);
}

extern "C" void kernel_launch(void* const* d_in, const int* in_sizes, int n_in,
                              void* d_out, int out_size, void* d_ws, size_t ws_size,
                              hipStream_t stream) {
    const int*   x       = (const int*)d_in[0];
    const int*   lenp    = (const int*)d_in[1];
    const float* emb     = (const float*)d_in[2];
    const float* w_ih    = (const float*)d_in[3];
    const float* w_hh    = (const float*)d_in[4];
    const float* b_ih    = (const float*)d_in[5];
    const float* b_hh    = (const float*)d_in[6];
    const float* dec_emb = (const float*)d_in[7];
    float* out = (float*)d_out;

    char* ws = (char*)d_ws;
    float* table = (float*)ws;                              // 6,291,456 B
    u64*   hbuf0 = (u64*)(ws + (size_t)VOCAB * H3 * 4);     // 2048 u64
    u64*   hbuf1 = hbuf0 + H_DIM;                           // 2048 u64

    // zero both tagged h buffers: h_0 = {tag 0, 0.0f} (ws poisoned 0xAA)
    hipMemsetAsync(hbuf0, 0, (size_t)2 * H_DIM * sizeof(u64), stream);

    dim3 gA(H3 / 64, VOCAB / 64);  // (96, 4)
    ih_table_kernel<<<gA, 256, 0, stream>>>(emb, w_ih, b_ih, table);

    gru_persistent<<<dim3(NCOMP), dim3(TPW), 0, stream>>>(
        x, lenp, w_hh, b_hh, table, hbuf0, hbuf1);

    epilogue_kernel<<<12, 256, 0, stream>>>(lenp, dec_emb, hbuf0, hbuf1, out);
}

// Round 11
// 2888.005 us; speedup vs baseline: 2.1417x; 2.1417x over previous
//
#include <hip/hip_runtime.h>
#include <hip/hip_bf16.h>
#include <math.h>

#define E_DIM 1024
#define H_DIM 2048
#define H3 6144
#define VOCAB 256
#define NCOMP 256          // one WG per CU
#define TPW 512            // 8 waves; wave uu owns hidden unit base+uu

typedef unsigned long long u64;

// ---------------- Phase A: table[v][j] = b_ih[j] + sum_e emb[v,e]*w_ih[j,e]
__global__ __launch_bounds__(256) void ih_table_kernel(
    const float* __restrict__ emb, const float* __restrict__ w_ih,
    const float* __restrict__ b_ih, float* __restrict__ table)
{
    __shared__ float As[32][65];
    __shared__ float Bs[32][65];
    const int v0 = blockIdx.y * 64;
    const int j0 = blockIdx.x * 64;
    const int t  = threadIdx.x;
    const int tx = t % 16, ty = t / 16;
    const int lr0 = t / 8;
    const int lc  = (t % 8) * 4;
    float acc[4][4] = {};

    for (int k0 = 0; k0 < E_DIM; k0 += 32) {
        __syncthreads();
#pragma unroll
        for (int p = 0; p < 2; ++p) {
            int r = lr0 + p * 32;
            float4 a = *(const float4*)(emb  + (size_t)(v0 + r) * E_DIM + k0 + lc);
            As[lc+0][r] = a.x; As[lc+1][r] = a.y; As[lc+2][r] = a.z; As[lc+3][r] = a.w;
            float4 b = *(const float4*)(w_ih + (size_t)(j0 + r) * E_DIM + k0 + lc);
            Bs[lc+0][r] = b.x; Bs[lc+1][r] = b.y; Bs[lc+2][r] = b.z; Bs[lc+3][r] = b.w;
        }
        __syncthreads();
#pragma unroll 8
        for (int kk = 0; kk < 32; ++kk) {
            float a4[4], b4[4];
#pragma unroll
            for (int i = 0; i < 4; ++i) a4[i] = As[kk][ty * 4 + i];
#pragma unroll
            for (int i = 0; i < 4; ++i) b4[i] = Bs[kk][tx * 4 + i];
#pragma unroll
            for (int i = 0; i < 4; ++i)
#pragma unroll
                for (int j = 0; j < 4; ++j) acc[i][j] += a4[i] * b4[j];
        }
    }
    const int j = j0 + tx * 4;
    float4 bias = *(const float4*)(b_ih + j);
#pragma unroll
    for (int i = 0; i < 4; ++i) {
        int v = v0 + ty * 4 + i;
        float4 o;
        o.x = acc[i][0] + bias.x; o.y = acc[i][1] + bias.y;
        o.z = acc[i][2] + bias.z; o.w = acc[i][3] + bias.w;
        *(float4*)(table + (size_t)v * H3 + j) = o;
    }
}

// ---------------- Phase B: persistent GRU, W_hh register-resident (R7 base).
// h exchanged as u64 {tag:32 | f32 bits:32}; tag==s marks h_s valid.
// Wave uu owns unit base+uu end-to-end: dot in registers, 64-lane shuffle
// reduce, lane 0 computes gates and publishes immediately. ONE barrier per
// step; hsh double-buffered for wave slip.
// R11: SLOT-CONTIGUOUS POLL — thread tid polls 4 CONSECUTIVE u64
// (half a 64B line) instead of 4 slots in 4 different lines:
//   * thread completion = ONE line event (producer wave's stores commit
//     together), not max of 4 independent arrivals
//   * per-line pollers drop 8 -> 2; same-line sweep loads MSHR-coalesce
//     into ~1 fetch -> ~4x less poll line-traffic (R5..R10: time/step
//     tracked poll fetch/step monotonically)
// No added in-flight depth (R9/R10 showed deeper polls worsen the drain).
__global__ __launch_bounds__(TPW, 2) void gru_persistent(
    const int* __restrict__ x, const int* __restrict__ lenp,
    const float* __restrict__ w_hh, const float* __restrict__ b_hh,
    const float* __restrict__ table,
    u64* hbuf0, u64* hbuf1)
{
    __shared__ float hsh[2][H_DIM];   // double-buffered staged h
    const int cw   = blockIdx.x;
    const int tid  = threadIdx.x;
    const int base = cw * 8;
    const int uu   = tid >> 6;     // wave id = owned unit
    const int l    = tid & 63;     // lane
    const int S    = lenp[0] + 1;  // 1025

    // one-time weight preload: 3 gates x 8 float4 = 96 regs, pinned
    float4 wv[3][8];
#pragma unroll
    for (int g = 0; g < 3; ++g) {
        const float4* wr =
            (const float4*)(w_hh + (size_t)(g * H_DIM + base + uu) * H_DIM);
#pragma unroll
        for (int i = 0; i < 8; ++i) wv[g][i] = wr[i * 64 + l];
    }
#pragma unroll
    for (int g = 0; g < 3; ++g)
#pragma unroll
        for (int i = 0; i < 8; ++i)
            asm volatile("" : "+v"(wv[g][i].x), "+v"(wv[g][i].y),
                              "+v"(wv[g][i].z), "+v"(wv[g][i].w));

    float bhr = 0.f, bhz = 0.f, bhn = 0.f;
    if (l == 0) {
        bhr = b_hh[base + uu];
        bhz = b_hh[H_DIM + base + uu];
        bhn = b_hh[2 * H_DIM + base + uu];
    }

    u64* bufs[2] = {hbuf0, hbuf1};

    for (int s = 0; s < S; ++s) {
        const u64* src = bufs[s & 1];
        u64*       dst = bufs[(s + 1) & 1];
        float*     hs  = hsh[s & 1];

        // input-side gate values: issue before the spin (latency overlaps)
        float ihr = 0.f, ihz = 0.f, ihn = 0.f;
        if (l == 0) {
            const float* trow = table + (size_t)x[s] * H3;
            ihr = trow[base + uu];
            ihz = trow[H_DIM + base + uu];
            ihn = trow[2 * H_DIM + base + uu];
        }

        // slot-contiguous poll+stage: thread owns u64s 4*tid .. 4*tid+3
        // (half a line) — the discovering load IS the data load
        {
            const unsigned want = (unsigned)s;
            const u64* ps = src + 4 * tid;
            float* hd = hs + 4 * tid;
            bool ok[4] = {false, false, false, false};
            int rem = 4;
            while (rem) {
#pragma unroll
                for (int j = 0; j < 4; ++j) {
                    if (!ok[j]) {
                        u64 v = __hip_atomic_load(ps + j, __ATOMIC_RELAXED,
                                                  __HIP_MEMORY_SCOPE_AGENT);
                        if ((unsigned)(v >> 32) == want) {
                            ok[j] = true; --rem;
                            hd[j] = __uint_as_float((unsigned)v);
                        }
                    }
                }
                if (rem) __builtin_amdgcn_s_sleep(1);
            }
        }
        __syncthreads();   // the ONLY barrier per step

        // fused-gate dot for unit base+uu: each h chunk read once, 3 FMAs
        const float4* h4 = (const float4*)hs;
        float4 ar = make_float4(0.f, 0.f, 0.f, 0.f);
        float4 az = make_float4(0.f, 0.f, 0.f, 0.f);
        float4 an = make_float4(0.f, 0.f, 0.f, 0.f);
#pragma unroll
        for (int i = 0; i < 8; ++i) {
            float4 hv = h4[i * 64 + l];
            ar.x += wv[0][i].x * hv.x; ar.y += wv[0][i].y * hv.y;
            ar.z += wv[0][i].z * hv.z; ar.w += wv[0][i].w * hv.w;
            az.x += wv[1][i].x * hv.x; az.y += wv[1][i].y * hv.y;
            az.z += wv[1][i].z * hv.z; az.w += wv[1][i].w * hv.w;
            an.x += wv[2][i].x * hv.x; an.y += wv[2][i].y * hv.y;
            an.z += wv[2][i].z * hv.z; an.w += wv[2][i].w * hv.w;
        }
        float pr = (ar.x + ar.y) + (ar.z + ar.w);
        float pz = (az.x + az.y) + (az.z + az.w);
        float pn = (an.x + an.y) + (an.z + an.w);
#pragma unroll
        for (int d = 1; d < 64; d <<= 1) {
            pr += __shfl_xor(pr, d);
            pz += __shfl_xor(pz, d);
            pn += __shfl_xor(pn, d);
        }

        // lane 0: gates + immediate publish
        if (l == 0) {
            float hprev = hs[base + uu];
            float hr = pr + bhr;
            float hz = pz + bhz;
            float hn = pn + bhn;
            float r_ = 1.f / (1.f + __expf(-(ihr + hr)));
            float z_ = 1.f / (1.f + __expf(-(ihz + hz)));
            float xn = ihn + r_ * hn;
            float axn = fabsf(xn), te = __expf(2.f * axn);
            float n_ = copysignf(1.f - 2.f / (te + 1.f), xn);
            float hnew = (1.f - z_) * n_ + z_ * hprev;
            u64 pack = ((u64)(unsigned)(s + 1) << 32) |
                       (u64)__float_as_uint(hnew);
            __hip_atomic_store(dst + base + uu, pack, __ATOMIC_RELAXED,
                               __HIP_MEMORY_SCOPE_AGENT);
        }
        // no trailing barrier: next step stages into the other hsh buffer
    }
}

// ---------------- Epilogue: out = [dec_emb[2] (1024) | h_final (2048)]
__global__ void epilogue_kernel(const int* __restrict__ lenp,
                                const float* __restrict__ dec_emb,
                                const u64* __restrict__ hbuf0,
                                const u64* __restrict__ hbuf1,
                                float* __restrict__ out)
{
    int i = blockIdx.x * blockDim.x + threadIdx.x;
    int S = lenp[0] + 1;
    const u64* hb = (S & 1) ? hbuf1 : hbuf0;
    if (i < E_DIM) out[i] = dec_emb[2 * E_DIM + i];
    else if (i < E_DIM + H_DIM)
        out[i] = __uint_as_float((unsigned)hb[i - E_DIM]);
}

extern "C" void kernel_launch(void* const* d_in, const int* in_sizes, int n_in,
                              void* d_out, int out_size, void* d_ws, size_t ws_size,
                              hipStream_t stream) {
    const int*   x       = (const int*)d_in[0];
    const int*   lenp    = (const int*)d_in[1];
    const float* emb     = (const float*)d_in[2];
    const float* w_ih    = (const float*)d_in[3];
    const float* w_hh    = (const float*)d_in[4];
    const float* b_ih    = (const float*)d_in[5];
    const float* b_hh    = (const float*)d_in[6];
    const float* dec_emb = (const float*)d_in[7];
    float* out = (float*)d_out;

    char* ws = (char*)d_ws;
    float* table = (float*)ws;                              // 6,291,456 B
    u64*   hbuf0 = (u64*)(ws + (size_t)VOCAB * H3 * 4);     // 2048 u64
    u64*   hbuf1 = hbuf0 + H_DIM;                           // 2048 u64

    // zero both tagged h buffers: h_0 = {tag 0, 0.0f} (ws poisoned 0xAA)
    hipMemsetAsync(hbuf0, 0, (size_t)2 * H_DIM * sizeof(u64), stream);

    dim3 gA(H3 / 64, VOCAB / 64);  // (96, 4)
    ih_table_kernel<<<gA, 256, 0, stream>>>(emb, w_ih, b_ih, table);

    gru_persistent<<<dim3(NCOMP), dim3(TPW), 0, stream>>>(
        x, lenp, w_hh, b_hh, table, hbuf0, hbuf1);

    epilogue_kernel<<<12, 256, 0, stream>>>(lenp, dec_emb, hbuf0, hbuf1, out);
}